// Round 2
// baseline (1475.938 us; speedup 1.0000x reference)
//
#include <hip/hip_runtime.h>
#include <math.h>

#define BATCH 4
#define CIN 64
#define HW 256
#define NPIX 65536       // 256*256
#define OC 192
#define TH 294
#define NPIX_R 86436     // 294*294
#define PS2 49
#define NWIN 36          // 6*6 windows per batch

// ---------------- K1: 1x1 conv (qkv) for ONE batch, 2 pixels/thread --------
__global__ __launch_bounds__(128)
void k_qkv1x1(const float* __restrict__ x, const float* __restrict__ w,
              float* __restrict__ A) {
    int pp = blockIdx.x * 128 + threadIdx.x;       // pixel pair in [0,32768)
    const float* xp = x + pp * 2;
    float xr0[CIN], xr1[CIN];
    #pragma unroll
    for (int c = 0; c < CIN; ++c) {
        float2 v = *reinterpret_cast<const float2*>(xp + (size_t)c * NPIX);
        xr0[c] = v.x; xr1[c] = v.y;
    }
    float* Ap = A + pp * 2;
    for (int o = 0; o < OC; ++o) {
        const float* wr = w + o * CIN;              // uniform -> s_load path
        float a0 = 0.f, a1 = 0.f;
        #pragma unroll
        for (int c = 0; c < CIN; ++c) {
            float wc = wr[c];
            a0 = fmaf(xr0[c], wc, a0);
            a1 = fmaf(xr1[c], wc, a1);
        }
        *reinterpret_cast<float2*>(Ap + (size_t)o * NPIX) = make_float2(a0, a1);
    }
}

// ---------------- K2: depthwise 3x3, ONE batch, 4 pixels/thread -------------
__global__ __launch_bounds__(256)
void k_dw3x3(const float* __restrict__ A, const float* __restrict__ dwv,
             float* __restrict__ Bf) {
    int gid = blockIdx.x * 256 + threadIdx.x;   // ch*16384 + quad
    int ch = gid >> 14;                          // [0,192)
    int q  = gid & 16383;
    int y  = q >> 6;
    int x4 = (q & 63) << 2;
    const float* Ap = A + (size_t)ch * NPIX;
    float wv[9];
    #pragma unroll
    for (int i = 0; i < 9; ++i) wv[i] = dwv[ch * 9 + i];
    float acc0 = 0.f, acc1 = 0.f, acc2 = 0.f, acc3 = 0.f;
    #pragma unroll
    for (int ky = 0; ky < 3; ++ky) {
        int yy = y + ky - 1;
        if (yy < 0 || yy >= HW) continue;
        const float* row = Ap + yy * HW;
        float cv[6];
        #pragma unroll
        for (int t = 0; t < 6; ++t) {
            int xx = x4 - 1 + t;
            cv[t] = (xx >= 0 && xx < HW) ? row[xx] : 0.f;
        }
        #pragma unroll
        for (int kx = 0; kx < 3; ++kx) {
            float wk = wv[ky * 3 + kx];
            acc0 = fmaf(cv[0 + kx], wk, acc0);
            acc1 = fmaf(cv[1 + kx], wk, acc1);
            acc2 = fmaf(cv[2 + kx], wk, acc2);
            acc3 = fmaf(cv[3 + kx], wk, acc3);
        }
    }
    *reinterpret_cast<float4*>(Bf + (size_t)ch * NPIX + y * HW + x4) =
        make_float4(acc0, acc1, acc2, acc3);
}

// ---------------- K3: fused bilinear-up + windowed cosine attention, ONE batch
// One block per (window, channel) = 36*64 = 2304 blocks.
__global__ __launch_bounds__(256)
void k_attn(const float* __restrict__ Bf, float* __restrict__ Cf) {
    __shared__ float Qs[PS2 * PS2];
    __shared__ float Ks[PS2 * PS2];
    __shared__ float Vs[PS2 * PS2];
    __shared__ float inq[PS2], ink[PS2];
    int n   = blockIdx.x;
    int ch  = n & 63;          // head*8 + d == image channel
    int win = n >> 6;          // [0,36)
    int xw  = win / 6;
    int yw  = win - xw * 6;
    const float* qb = Bf + (size_t)ch * NPIX;
    const float* kb = qb + (size_t)64  * NPIX;
    const float* vb = qb + (size_t)128 * NPIX;
    const float scale = 255.0f / 293.0f;        // align_corners=True, 256->294
    int tid = threadIdx.x;

    // load windows with fused bilinear; einops perm i=(cl/7)*7+rl%7, j=(cl%7)*7+rl/7
    for (int e = tid; e < PS2 * PS2; e += 256) {
        int rl = e / PS2;
        int cl = e - rl * PS2;
        int gy = xw * PS2 + rl, gx = yw * PS2 + cl;
        float sy = gy * scale, sx = gx * scale;
        int y0 = (int)sy, x0 = (int)sx;         // sy,sx >= 0
        float ly = sy - y0, lx = sx - x0;
        int y1 = min(y0 + 1, HW - 1), x1 = min(x0 + 1, HW - 1);
        float w00 = (1.f - ly) * (1.f - lx), w01 = (1.f - ly) * lx;
        float w10 = ly * (1.f - lx),         w11 = ly * lx;
        int o00 = y0 * HW + x0, o01 = y0 * HW + x1;
        int o10 = y1 * HW + x0, o11 = y1 * HW + x1;
        int i = (cl / 7) * 7 + (rl % 7);
        int j = (cl % 7) * 7 + (rl / 7);
        int d = i * PS2 + j;
        Qs[d] = qb[o00] * w00 + qb[o01] * w01 + qb[o10] * w10 + qb[o11] * w11;
        Ks[d] = kb[o00] * w00 + kb[o01] * w01 + kb[o10] * w10 + kb[o11] * w11;
        Vs[d] = vb[o00] * w00 + vb[o01] * w01 + vb[o10] * w10 + vb[o11] * w11;
    }
    __syncthreads();

    // inverse row L2 norms, eps=1e-12 (F.normalize)
    if (tid < PS2) {
        float s = 0.f;
        for (int jj = 0; jj < PS2; ++jj) { float v = Qs[tid * PS2 + jj]; s = fmaf(v, v, s); }
        inq[tid] = 1.f / fmaxf(sqrtf(s), 1e-12f);
    } else if (tid >= 64 && tid < 64 + PS2) {
        int t = tid - 64;
        float s = 0.f;
        for (int jj = 0; jj < PS2; ++jj) { float v = Ks[t * PS2 + jj]; s = fmaf(v, v, s); }
        ink[t] = 1.f / fmaxf(sqrtf(s), 1e-12f);
    }
    __syncthreads();

    // one attention row per wave-iteration; lane l owns column l (l<49)
    int wv = tid >> 6, lane = tid & 63;
    for (int i = wv; i < PS2; i += 4) {
        float sval = -INFINITY;
        if (lane < PS2) {
            float dot = 0.f;
            for (int jj = 0; jj < PS2; ++jj)
                dot = fmaf(Qs[i * PS2 + jj], Ks[lane * PS2 + jj], dot);
            sval = dot * inq[i] * ink[lane];
        }
        float m = sval;
        #pragma unroll
        for (int off = 32; off; off >>= 1) m = fmaxf(m, __shfl_xor(m, off));
        float ev = (lane < PS2) ? __expf(sval - m) : 0.f;
        float ssum = ev;
        #pragma unroll
        for (int off = 32; off; off >>= 1) ssum += __shfl_xor(ssum, off);
        float pv = ev / ssum;
        float oacc = 0.f;
        for (int i2 = 0; i2 < PS2; ++i2) {
            float p = __shfl(pv, i2);            // broadcast P[i][i2]
            if (lane < PS2) oacc = fmaf(p, Vs[i2 * PS2 + lane], oacc);
        }
        if (lane < PS2) Qs[i * PS2 + lane] = oacc;   // Q row i dead after its S
    }
    __syncthreads();

    // inverse window permutation -> resized layout C (64,294,294)
    float* cb = Cf + (size_t)ch * NPIX_R;
    for (int e = tid; e < PS2 * PS2; e += 256) {
        int rl = e / PS2;
        int cl = e - rl * PS2;
        int i = (cl / 7) * 7 + (rl % 7);
        int j = (cl % 7) * 7 + (rl / 7);
        cb[(xw * PS2 + rl) * TH + (yw * PS2 + cl)] = Qs[i * PS2 + j];
    }
}

// ------- K4: bilinear down 294->256 (align_corners=False) + proj, ONE batch --
__global__ __launch_bounds__(256)
void k_proj(const float* __restrict__ Cf, const float* __restrict__ pw,
            float* __restrict__ out) {
    int p = blockIdx.x * 256 + threadIdx.x;     // [0,65536)
    int y = p >> 8, xx = p & 255;
    const float sc = 294.0f / 256.0f;
    float sy = fmaxf((y + 0.5f) * sc - 0.5f, 0.f);
    float sx = fmaxf((xx + 0.5f) * sc - 0.5f, 0.f);
    int y0 = (int)sy, x0 = (int)sx;
    float ly = sy - y0, lx = sx - x0;
    int y1 = min(y0 + 1, TH - 1), x1 = min(x0 + 1, TH - 1);
    float w00 = (1.f - ly) * (1.f - lx), w01 = (1.f - ly) * lx;
    float w10 = ly * (1.f - lx),         w11 = ly * lx;
    int o00 = y0 * TH + x0, o01 = y0 * TH + x1;
    int o10 = y1 * TH + x0, o11 = y1 * TH + x1;
    float rv[CIN];
    #pragma unroll
    for (int c = 0; c < CIN; ++c) {
        const float* cp = Cf + (size_t)c * NPIX_R;
        rv[c] = cp[o00] * w00 + cp[o01] * w01 + cp[o10] * w10 + cp[o11] * w11;
    }
    float* op = out + p;
    for (int o = 0; o < CIN; ++o) {
        const float* wr = pw + o * CIN;             // uniform -> s_load path
        float acc = 0.f;
        #pragma unroll
        for (int c = 0; c < CIN; ++c) acc = fmaf(rv[c], wr[c], acc);
        op[(size_t)o * NPIX] = acc;
    }
}

// ---------------- launch: per-batch pipeline, peak ws = 96 MB ----------------
extern "C" void kernel_launch(void* const* d_in, const int* in_sizes, int n_in,
                              void* d_out, int out_size, void* d_ws, size_t ws_size,
                              hipStream_t stream) {
    const float* x   = (const float*)d_in[0];   // (4,64,256,256)
    const float* qw  = (const float*)d_in[1];   // (192,64)
    const float* dwv = (const float*)d_in[2];   // (192,1,3,3)
    const float* pw  = (const float*)d_in[3];   // (64,64)
    float* out = (float*)d_out;                 // (4,64,256,256) fp32

    // per-batch workspace: A[192*65536] | B[192*65536]; C aliases A
    // (A dead after k_dw3x3). Peak = 100,663,296 bytes (96 MB).
    float* A = (float*)d_ws;
    float* B = A + (size_t)OC * NPIX;
    float* C = A;

    for (int b = 0; b < BATCH; ++b) {
        const float* xb = x + (size_t)b * CIN * NPIX;
        float* ob = out + (size_t)b * CIN * NPIX;
        hipLaunchKernelGGL(k_qkv1x1, dim3(256),   dim3(128), 0, stream, xb, qw, A);
        hipLaunchKernelGGL(k_dw3x3,  dim3(12288), dim3(256), 0, stream, A, dwv, B);
        hipLaunchKernelGGL(k_attn,   dim3(2304),  dim3(256), 0, stream, B, C);
        hipLaunchKernelGGL(k_proj,   dim3(256),   dim3(256), 0, stream, C, pw, ob);
    }
}

// Round 3
// 1100.734 us; speedup vs baseline: 1.3409x; 1.3409x over previous
//
#include <hip/hip_runtime.h>
#include <math.h>

#define BATCH 4
#define CIN 64
#define HW 256
#define NPIX 65536       // 256*256
#define OC 192
#define TH 294
#define NPIX_R 86436     // 294*294
#define PS2 49
#define NWIN 36          // 6*6 windows per batch

// ---------------- K1: 1x1 conv (qkv), ONE batch, oc-split x4 ----------------
// grid 1024 = 256 pixel-blocks x 4 oc-groups; 1 px/thread, 48 oc/thread.
__global__ __launch_bounds__(256)
void k_qkv1x1(const float* __restrict__ x, const float* __restrict__ w,
              float* __restrict__ A) {
    int bid   = blockIdx.x;
    int split = bid & 3;                         // oc group [0,4)
    int px    = (bid >> 2) * 256 + threadIdx.x;  // [0,65536)
    float xr[CIN];
    #pragma unroll
    for (int c = 0; c < CIN; ++c) xr[c] = x[(size_t)c * NPIX + px];
    const float* wbase = w + (size_t)split * 48 * CIN;
    float* Ap = A + (size_t)split * 48 * NPIX + px;
    #pragma unroll 4
    for (int o = 0; o < 48; ++o) {
        const float* wr = wbase + o * CIN;       // uniform -> s_load path
        float a = 0.f;
        #pragma unroll
        for (int c = 0; c < CIN; ++c) a = fmaf(xr[c], wr[c], a);
        Ap[(size_t)o * NPIX] = a;
    }
}

// ---------------- K2: depthwise 3x3, ONE batch, 4 pixels/thread -------------
__global__ __launch_bounds__(256)
void k_dw3x3(const float* __restrict__ A, const float* __restrict__ dwv,
             float* __restrict__ Bf) {
    int gid = blockIdx.x * 256 + threadIdx.x;   // ch*16384 + quad
    int ch = gid >> 14;                          // [0,192)
    int q  = gid & 16383;
    int y  = q >> 6;
    int x4 = (q & 63) << 2;
    const float* Ap = A + (size_t)ch * NPIX;
    float wv[9];
    #pragma unroll
    for (int i = 0; i < 9; ++i) wv[i] = dwv[ch * 9 + i];
    float acc0 = 0.f, acc1 = 0.f, acc2 = 0.f, acc3 = 0.f;
    #pragma unroll
    for (int ky = 0; ky < 3; ++ky) {
        int yy = y + ky - 1;
        if (yy < 0 || yy >= HW) continue;
        const float* row = Ap + yy * HW;
        float cv[6];
        #pragma unroll
        for (int t = 0; t < 6; ++t) {
            int xx = x4 - 1 + t;
            cv[t] = (xx >= 0 && xx < HW) ? row[xx] : 0.f;
        }
        #pragma unroll
        for (int kx = 0; kx < 3; ++kx) {
            float wk = wv[ky * 3 + kx];
            acc0 = fmaf(cv[0 + kx], wk, acc0);
            acc1 = fmaf(cv[1 + kx], wk, acc1);
            acc2 = fmaf(cv[2 + kx], wk, acc2);
            acc3 = fmaf(cv[3 + kx], wk, acc3);
        }
    }
    *reinterpret_cast<float4*>(Bf + (size_t)ch * NPIX + y * HW + x4) =
        make_float4(acc0, acc1, acc2, acc3);
}

// ---------------- K3: fused bilinear-up + windowed cosine attention, ONE batch
// One block per (window, channel) = 36*64 = 2304 blocks.
__global__ __launch_bounds__(256)
void k_attn(const float* __restrict__ Bf, float* __restrict__ Cf) {
    __shared__ float Qs[PS2 * PS2];
    __shared__ float Ks[PS2 * PS2];
    __shared__ float Vs[PS2 * PS2];
    __shared__ float inq[PS2], ink[PS2];
    __shared__ float Ps[4][64];                 // per-wave P row for PV broadcast
    int n   = blockIdx.x;
    int ch  = n & 63;          // head*8 + d == image channel
    int win = n >> 6;          // [0,36)
    int xw  = win / 6;
    int yw  = win - xw * 6;
    const float* qb = Bf + (size_t)ch * NPIX;
    const float* kb = qb + (size_t)64  * NPIX;
    const float* vb = qb + (size_t)128 * NPIX;
    const float scale = 255.0f / 293.0f;        // align_corners=True, 256->294
    int tid = threadIdx.x;

    // load windows with fused bilinear; einops perm i=(cl/7)*7+rl%7, j=(cl%7)*7+rl/7
    for (int e = tid; e < PS2 * PS2; e += 256) {
        int rl = e / PS2;
        int cl = e - rl * PS2;
        int gy = xw * PS2 + rl, gx = yw * PS2 + cl;
        float sy = gy * scale, sx = gx * scale;
        int y0 = (int)sy, x0 = (int)sx;         // sy,sx >= 0
        float ly = sy - y0, lx = sx - x0;
        int y1 = min(y0 + 1, HW - 1), x1 = min(x0 + 1, HW - 1);
        float w00 = (1.f - ly) * (1.f - lx), w01 = (1.f - ly) * lx;
        float w10 = ly * (1.f - lx),         w11 = ly * lx;
        int o00 = y0 * HW + x0, o01 = y0 * HW + x1;
        int o10 = y1 * HW + x0, o11 = y1 * HW + x1;
        int i = (cl / 7) * 7 + (rl % 7);
        int j = (cl % 7) * 7 + (rl / 7);
        int d = i * PS2 + j;
        Qs[d] = qb[o00] * w00 + qb[o01] * w01 + qb[o10] * w10 + qb[o11] * w11;
        Ks[d] = kb[o00] * w00 + kb[o01] * w01 + kb[o10] * w10 + kb[o11] * w11;
        Vs[d] = vb[o00] * w00 + vb[o01] * w01 + vb[o10] * w10 + vb[o11] * w11;
    }
    __syncthreads();

    // inverse row L2 norms, eps=1e-12 (F.normalize)
    if (tid < PS2) {
        float s = 0.f;
        for (int jj = 0; jj < PS2; ++jj) { float v = Qs[tid * PS2 + jj]; s = fmaf(v, v, s); }
        inq[tid] = 1.f / fmaxf(sqrtf(s), 1e-12f);
    } else if (tid >= 64 && tid < 64 + PS2) {
        int t = tid - 64;
        float s = 0.f;
        for (int jj = 0; jj < PS2; ++jj) { float v = Ks[t * PS2 + jj]; s = fmaf(v, v, s); }
        ink[t] = 1.f / fmaxf(sqrtf(s), 1e-12f);
    }
    __syncthreads();

    // one attention row per wave-iteration; lane l owns column l (l<49)
    int wv = tid >> 6, lane = tid & 63;
    for (int i = wv; i < PS2; i += 4) {
        float sval = -INFINITY;
        if (lane < PS2) {
            float dot = 0.f;
            for (int jj = 0; jj < PS2; ++jj)
                dot = fmaf(Qs[i * PS2 + jj], Ks[lane * PS2 + jj], dot);
            sval = dot * inq[i] * ink[lane];
        }
        float m = sval;
        #pragma unroll
        for (int off = 32; off; off >>= 1) m = fmaxf(m, __shfl_xor(m, off));
        float ev = (lane < PS2) ? __expf(sval - m) : 0.f;
        float ssum = ev;
        #pragma unroll
        for (int off = 32; off; off >>= 1) ssum += __shfl_xor(ssum, off);
        Ps[wv][lane] = ev / ssum;               // same-wave write, lockstep
        float oacc = 0.f;
        if (lane < PS2) {
            for (int i2 = 0; i2 < PS2; ++i2)    // LDS broadcast (conflict-free)
                oacc = fmaf(Ps[wv][i2], Vs[i2 * PS2 + lane], oacc);
            Qs[i * PS2 + lane] = oacc;          // Q row i dead after its S
        }
    }
    __syncthreads();

    // inverse window permutation -> resized layout C (64,294,294)
    float* cb = Cf + (size_t)ch * NPIX_R;
    for (int e = tid; e < PS2 * PS2; e += 256) {
        int rl = e / PS2;
        int cl = e - rl * PS2;
        int i = (cl / 7) * 7 + (rl % 7);
        int j = (cl % 7) * 7 + (rl / 7);
        cb[(xw * PS2 + rl) * TH + (yw * PS2 + cl)] = Qs[i * PS2 + j];
    }
}

// ------- K4: bilinear down 294->256 (align_corners=False) + proj, ONE batch --
// grid 512 = 256 pixel-blocks x 2 oc-halves.
__global__ __launch_bounds__(256)
void k_proj(const float* __restrict__ Cf, const float* __restrict__ pw,
            float* __restrict__ out) {
    int gid  = blockIdx.x * 256 + threadIdx.x;  // [0, 131072)
    int half = gid >> 16;                        // 0/1
    int p    = gid & 65535;
    int y = p >> 8, xx = p & 255;
    const float sc = 294.0f / 256.0f;
    float sy = fmaxf((y + 0.5f) * sc - 0.5f, 0.f);
    float sx = fmaxf((xx + 0.5f) * sc - 0.5f, 0.f);
    int y0 = (int)sy, x0 = (int)sx;
    float ly = sy - y0, lx = sx - x0;
    int y1 = min(y0 + 1, TH - 1), x1 = min(x0 + 1, TH - 1);
    float w00 = (1.f - ly) * (1.f - lx), w01 = (1.f - ly) * lx;
    float w10 = ly * (1.f - lx),         w11 = ly * lx;
    int o00 = y0 * TH + x0, o01 = y0 * TH + x1;
    int o10 = y1 * TH + x0, o11 = y1 * TH + x1;
    float rv[CIN];
    #pragma unroll
    for (int c = 0; c < CIN; ++c) {
        const float* cp = Cf + (size_t)c * NPIX_R;
        rv[c] = cp[o00] * w00 + cp[o01] * w01 + cp[o10] * w10 + cp[o11] * w11;
    }
    float* op = out + (size_t)half * 32 * NPIX + p;
    for (int o = 0; o < 32; ++o) {
        const float* wr = pw + (half * 32 + o) * CIN;   // uniform -> s_load
        float acc = 0.f;
        #pragma unroll
        for (int c = 0; c < CIN; ++c) acc = fmaf(rv[c], wr[c], acc);
        op[(size_t)o * NPIX] = acc;
    }
}

// ---------------- launch: per-batch pipeline, peak ws = 96 MB ----------------
extern "C" void kernel_launch(void* const* d_in, const int* in_sizes, int n_in,
                              void* d_out, int out_size, void* d_ws, size_t ws_size,
                              hipStream_t stream) {
    const float* x   = (const float*)d_in[0];   // (4,64,256,256)
    const float* qw  = (const float*)d_in[1];   // (192,64)
    const float* dwv = (const float*)d_in[2];   // (192,1,3,3)
    const float* pw  = (const float*)d_in[3];   // (64,64)
    float* out = (float*)d_out;                 // (4,64,256,256) fp32

    // per-batch workspace: A[192*65536] | B[192*65536]; C aliases A
    // (A dead after k_dw3x3). Peak = 100,663,296 bytes (96 MB).
    float* A = (float*)d_ws;
    float* B = A + (size_t)OC * NPIX;
    float* C = A;

    for (int b = 0; b < BATCH; ++b) {
        const float* xb = x + (size_t)b * CIN * NPIX;
        float* ob = out + (size_t)b * CIN * NPIX;
        hipLaunchKernelGGL(k_qkv1x1, dim3(1024),  dim3(256), 0, stream, xb, qw, A);
        hipLaunchKernelGGL(k_dw3x3,  dim3(12288), dim3(256), 0, stream, A, dwv, B);
        hipLaunchKernelGGL(k_attn,   dim3(2304),  dim3(256), 0, stream, B, C);
        hipLaunchKernelGGL(k_proj,   dim3(512),   dim3(256), 0, stream, C, pw, ob);
    }
}

// Round 4
// 921.062 us; speedup vs baseline: 1.6024x; 1.1951x over previous
//
#include <hip/hip_runtime.h>
#include <math.h>

#define BATCH 4
#define CIN 64
#define HW 256
#define NPIX 65536       // 256*256
#define OC 192
#define TH 294
#define NPIX_R 86436     // 294*294
#define PS2 49
#define NWIN 36          // 6*6 windows per batch

// ---------------- K1: 1x1 conv (qkv) as LDS-tiled GEMM ----------------------
// M=192 oc x K=64 x N=65536 px. Block tile: 64 oc x 256 px. Thread: 4 oc x 16 px.
// grid (256 px-tiles, 3 oc-tiles, nb)
__global__ __launch_bounds__(256)
void k_qkv1x1(const float* __restrict__ x, const float* __restrict__ w,
              float* __restrict__ A) {
    __shared__ float wT[64][64];     // wT[c][o] (transposed for contiguous oc)
    __shared__ float xs[64][256];    // xs[c][px]
    x += (size_t)blockIdx.z * CIN * NPIX;
    A += (size_t)blockIdx.z * OC * NPIX;
    const int tid = threadIdx.x;
    const int pxbase = blockIdx.x * 256;
    const int ocbase = blockIdx.y * 64;

    for (int idx = tid; idx < 1024; idx += 256) {        // 64 oc x 16 float4
        int o = idx >> 4, c4 = idx & 15;
        float4 v = *reinterpret_cast<const float4*>(w + (size_t)(ocbase + o) * CIN + c4 * 4);
        wT[c4 * 4 + 0][o] = v.x; wT[c4 * 4 + 1][o] = v.y;
        wT[c4 * 4 + 2][o] = v.z; wT[c4 * 4 + 3][o] = v.w;
    }
    for (int idx = tid; idx < 4096; idx += 256) {        // 64 c x 64 float4
        int c = idx >> 6, p4 = idx & 63;
        float4 v = *reinterpret_cast<const float4*>(x + (size_t)c * NPIX + pxbase + p4 * 4);
        *reinterpret_cast<float4*>(&xs[c][p4 * 4]) = v;
    }
    __syncthreads();

    const int tx = tid & 15, ty = tid >> 4;
    float acc[4][16];
    #pragma unroll
    for (int a = 0; a < 4; ++a)
        #pragma unroll
        for (int b = 0; b < 16; ++b) acc[a][b] = 0.f;

    #pragma unroll 4
    for (int k = 0; k < 64; ++k) {
        float4 wv = *reinterpret_cast<const float4*>(&wT[k][ty * 4]);
        float wr[4] = {wv.x, wv.y, wv.z, wv.w};
        float xv[16];
        #pragma unroll
        for (int i = 0; i < 4; ++i) {                    // px = tx*4 + i*64
            float4 v = *reinterpret_cast<const float4*>(&xs[k][tx * 4 + i * 64]);
            xv[i * 4 + 0] = v.x; xv[i * 4 + 1] = v.y;
            xv[i * 4 + 2] = v.z; xv[i * 4 + 3] = v.w;
        }
        #pragma unroll
        for (int a = 0; a < 4; ++a)
            #pragma unroll
            for (int b = 0; b < 16; ++b)
                acc[a][b] = fmaf(wr[a], xv[b], acc[a][b]);
    }

    #pragma unroll
    for (int a = 0; a < 4; ++a) {
        float* Ap = A + (size_t)(ocbase + ty * 4 + a) * NPIX + pxbase;
        #pragma unroll
        for (int i = 0; i < 4; ++i)
            *reinterpret_cast<float4*>(Ap + tx * 4 + i * 64) =
                make_float4(acc[a][i * 4 + 0], acc[a][i * 4 + 1],
                            acc[a][i * 4 + 2], acc[a][i * 4 + 3]);
    }
}

// ---------------- K2: depthwise 3x3, 4 pixels/thread ------------------------
__global__ __launch_bounds__(256)
void k_dw3x3(const float* __restrict__ A, const float* __restrict__ dwv,
             float* __restrict__ Bf) {
    A  += (size_t)blockIdx.z * OC * NPIX;
    Bf += (size_t)blockIdx.z * OC * NPIX;
    int gid = blockIdx.x * 256 + threadIdx.x;   // ch*16384 + quad
    int ch = gid >> 14;                          // [0,192)
    int q  = gid & 16383;
    int y  = q >> 6;
    int x4 = (q & 63) << 2;
    const float* Ap = A + (size_t)ch * NPIX;
    float wv[9];
    #pragma unroll
    for (int i = 0; i < 9; ++i) wv[i] = dwv[ch * 9 + i];
    float acc0 = 0.f, acc1 = 0.f, acc2 = 0.f, acc3 = 0.f;
    #pragma unroll
    for (int ky = 0; ky < 3; ++ky) {
        int yy = y + ky - 1;
        if (yy < 0 || yy >= HW) continue;
        const float* row = Ap + yy * HW;
        float cv[6];
        #pragma unroll
        for (int t = 0; t < 6; ++t) {
            int xx = x4 - 1 + t;
            cv[t] = (xx >= 0 && xx < HW) ? row[xx] : 0.f;
        }
        #pragma unroll
        for (int kx = 0; kx < 3; ++kx) {
            float wk = wv[ky * 3 + kx];
            acc0 = fmaf(cv[0 + kx], wk, acc0);
            acc1 = fmaf(cv[1 + kx], wk, acc1);
            acc2 = fmaf(cv[2 + kx], wk, acc2);
            acc3 = fmaf(cv[3 + kx], wk, acc3);
        }
    }
    *reinterpret_cast<float4*>(Bf + (size_t)ch * NPIX + y * HW + x4) =
        make_float4(acc0, acc1, acc2, acc3);
}

// ---------------- K3: fused bilinear-up + windowed cosine attention ---------
// One block per (window, channel) = 36*64 blocks per batch.
__global__ __launch_bounds__(256)
void k_attn(const float* __restrict__ Bf, float* __restrict__ Cf) {
    __shared__ float Qs[PS2 * PS2];
    __shared__ float Ks[PS2 * PS2];
    __shared__ float Vs[PS2 * PS2];
    __shared__ float inq[PS2], ink[PS2];
    __shared__ float Ps[4][64];                 // per-wave P row for PV broadcast
    Bf += (size_t)blockIdx.z * OC * NPIX;
    Cf += (size_t)blockIdx.z * CIN * NPIX_R;
    int n   = blockIdx.x;
    int ch  = n & 63;          // head*8 + d == image channel
    int win = n >> 6;          // [0,36)
    int xw  = win / 6;
    int yw  = win - xw * 6;
    const float* qb = Bf + (size_t)ch * NPIX;
    const float* kb = qb + (size_t)64  * NPIX;
    const float* vb = qb + (size_t)128 * NPIX;
    const float scale = 255.0f / 293.0f;        // align_corners=True, 256->294
    int tid = threadIdx.x;

    // load windows with fused bilinear; einops perm i=(cl/7)*7+rl%7, j=(cl%7)*7+rl/7
    for (int e = tid; e < PS2 * PS2; e += 256) {
        int rl = e / PS2;
        int cl = e - rl * PS2;
        int gy = xw * PS2 + rl, gx = yw * PS2 + cl;
        float sy = gy * scale, sx = gx * scale;
        int y0 = (int)sy, x0 = (int)sx;         // sy,sx >= 0
        float ly = sy - y0, lx = sx - x0;
        int y1 = min(y0 + 1, HW - 1), x1 = min(x0 + 1, HW - 1);
        float w00 = (1.f - ly) * (1.f - lx), w01 = (1.f - ly) * lx;
        float w10 = ly * (1.f - lx),         w11 = ly * lx;
        int o00 = y0 * HW + x0, o01 = y0 * HW + x1;
        int o10 = y1 * HW + x0, o11 = y1 * HW + x1;
        int i = (cl / 7) * 7 + (rl % 7);
        int j = (cl % 7) * 7 + (rl / 7);
        int d = i * PS2 + j;
        Qs[d] = qb[o00] * w00 + qb[o01] * w01 + qb[o10] * w10 + qb[o11] * w11;
        Ks[d] = kb[o00] * w00 + kb[o01] * w01 + kb[o10] * w10 + kb[o11] * w11;
        Vs[d] = vb[o00] * w00 + vb[o01] * w01 + vb[o10] * w10 + vb[o11] * w11;
    }
    __syncthreads();

    // inverse row L2 norms, eps=1e-12 (F.normalize)
    if (tid < PS2) {
        float s = 0.f;
        for (int jj = 0; jj < PS2; ++jj) { float v = Qs[tid * PS2 + jj]; s = fmaf(v, v, s); }
        inq[tid] = 1.f / fmaxf(sqrtf(s), 1e-12f);
    } else if (tid >= 64 && tid < 64 + PS2) {
        int t = tid - 64;
        float s = 0.f;
        for (int jj = 0; jj < PS2; ++jj) { float v = Ks[t * PS2 + jj]; s = fmaf(v, v, s); }
        ink[t] = 1.f / fmaxf(sqrtf(s), 1e-12f);
    }
    __syncthreads();

    // one attention row per wave-iteration; lane l owns column l (l<49)
    int wv = tid >> 6, lane = tid & 63;
    for (int i = wv; i < PS2; i += 4) {
        float sval = -INFINITY;
        if (lane < PS2) {
            float dot = 0.f;
            for (int jj = 0; jj < PS2; ++jj)
                dot = fmaf(Qs[i * PS2 + jj], Ks[lane * PS2 + jj], dot);
            sval = dot * inq[i] * ink[lane];
        }
        float m = sval;
        #pragma unroll
        for (int off = 32; off; off >>= 1) m = fmaxf(m, __shfl_xor(m, off));
        float ev = (lane < PS2) ? __expf(sval - m) : 0.f;
        float ssum = ev;
        #pragma unroll
        for (int off = 32; off; off >>= 1) ssum += __shfl_xor(ssum, off);
        Ps[wv][lane] = ev / ssum;               // same-wave write, lockstep
        float oacc = 0.f;
        if (lane < PS2) {
            for (int i2 = 0; i2 < PS2; ++i2)    // LDS broadcast (conflict-free)
                oacc = fmaf(Ps[wv][i2], Vs[i2 * PS2 + lane], oacc);
            Qs[i * PS2 + lane] = oacc;          // Q row i dead after its S
        }
    }
    __syncthreads();

    // inverse window permutation -> resized layout C (64,294,294)
    float* cb = Cf + (size_t)ch * NPIX_R;
    for (int e = tid; e < PS2 * PS2; e += 256) {
        int rl = e / PS2;
        int cl = e - rl * PS2;
        int i = (cl / 7) * 7 + (rl % 7);
        int j = (cl % 7) * 7 + (rl / 7);
        cb[(xw * PS2 + rl) * TH + (yw * PS2 + cl)] = Qs[i * PS2 + j];
    }
}

// ------- K4: bilinear down 294->256 (align_corners=False) + proj ------------
// grid (512, 1, nb) = 256 pixel-blocks x 2 oc-halves.
__global__ __launch_bounds__(256)
void k_proj(const float* __restrict__ Cf, const float* __restrict__ pw,
            float* __restrict__ out) {
    Cf  += (size_t)blockIdx.z * CIN * NPIX_R;
    out += (size_t)blockIdx.z * CIN * NPIX;
    int gid  = blockIdx.x * 256 + threadIdx.x;  // [0, 131072)
    int half = gid >> 16;                        // 0/1
    int p    = gid & 65535;
    int y = p >> 8, xx = p & 255;
    const float sc = 294.0f / 256.0f;
    float sy = fmaxf((y + 0.5f) * sc - 0.5f, 0.f);
    float sx = fmaxf((xx + 0.5f) * sc - 0.5f, 0.f);
    int y0 = (int)sy, x0 = (int)sx;
    float ly = sy - y0, lx = sx - x0;
    int y1 = min(y0 + 1, TH - 1), x1 = min(x0 + 1, TH - 1);
    float w00 = (1.f - ly) * (1.f - lx), w01 = (1.f - ly) * lx;
    float w10 = ly * (1.f - lx),         w11 = ly * lx;
    int o00 = y0 * TH + x0, o01 = y0 * TH + x1;
    int o10 = y1 * TH + x0, o11 = y1 * TH + x1;
    float rv[CIN];
    #pragma unroll
    for (int c = 0; c < CIN; ++c) {
        const float* cp = Cf + (size_t)c * NPIX_R;
        rv[c] = cp[o00] * w00 + cp[o01] * w01 + cp[o10] * w10 + cp[o11] * w11;
    }
    float* op = out + (size_t)half * 32 * NPIX + p;
    for (int o = 0; o < 32; ++o) {
        const float* wr = pw + (half * 32 + o) * CIN;   // uniform -> s_load
        float acc = 0.f;
        #pragma unroll
        for (int c = 0; c < CIN; ++c) acc = fmaf(rv[c], wr[c], acc);
        op[(size_t)o * NPIX] = acc;
    }
}

// ---------------- launch --------------------------------------------------
extern "C" void kernel_launch(void* const* d_in, const int* in_sizes, int n_in,
                              void* d_out, int out_size, void* d_ws, size_t ws_size,
                              hipStream_t stream) {
    const float* x   = (const float*)d_in[0];   // (4,64,256,256)
    const float* qw  = (const float*)d_in[1];   // (192,64)
    const float* dwv = (const float*)d_in[2];   // (192,1,3,3)
    const float* pw  = (const float*)d_in[3];   // (64,64)
    float* out = (float*)d_out;                 // (4,64,256,256) fp32

    const size_t perAB = (size_t)OC * NPIX;     // floats per batch for A or B
    const size_t needBig = (size_t)2 * BATCH * perAB * sizeof(float);  // 384 MB

    if (ws_size >= needBig) {
        // batch-parallel: A[4x48MB] | B[4x48MB]; C (4x21MB) aliases A
        float* A = (float*)d_ws;
        float* B = A + BATCH * perAB;
        float* C = A;
        hipLaunchKernelGGL(k_qkv1x1, dim3(256, 3, BATCH),  dim3(256), 0, stream, x, qw, A);
        hipLaunchKernelGGL(k_dw3x3,  dim3(12288, 1, BATCH), dim3(256), 0, stream, A, dwv, B);
        hipLaunchKernelGGL(k_attn,   dim3(2304, 1, BATCH),  dim3(256), 0, stream, B, C);
        hipLaunchKernelGGL(k_proj,   dim3(512, 1, BATCH),   dim3(256), 0, stream, C, pw, out);
    } else {
        // per-batch: A | B per batch (96 MB); C aliases A (dead after k_dw3x3)
        float* A = (float*)d_ws;
        float* B = A + perAB;
        float* C = A;
        for (int b = 0; b < BATCH; ++b) {
            const float* xb = x + (size_t)b * CIN * NPIX;
            float* ob = out + (size_t)b * CIN * NPIX;
            hipLaunchKernelGGL(k_qkv1x1, dim3(256, 3, 1),  dim3(256), 0, stream, xb, qw, A);
            hipLaunchKernelGGL(k_dw3x3,  dim3(12288, 1, 1), dim3(256), 0, stream, A, dwv, B);
            hipLaunchKernelGGL(k_attn,   dim3(2304, 1, 1),  dim3(256), 0, stream, B, C);
            hipLaunchKernelGGL(k_proj,   dim3(512, 1, 1),   dim3(256), 0, stream, C, pw, ob);
        }
    }
}

// Round 5
// 830.176 us; speedup vs baseline: 1.7779x; 1.1095x over previous
//
#include <hip/hip_runtime.h>
#include <math.h>

#define BATCH 4
#define CIN 64
#define HW 256
#define NPIX 65536       // 256*256
#define OC 192
#define TH 294
#define NPIX_R 86436     // 294*294
#define PS2 49
#define LSTR 52          // padded LDS row stride (52*4 B = 208, 16B-aligned)
#define NWIN 36          // 6*6 windows per batch

// ---------------- K1: 1x1 conv (qkv) as LDS-tiled GEMM ----------------------
__global__ __launch_bounds__(256)
void k_qkv1x1(const float* __restrict__ x, const float* __restrict__ w,
              float* __restrict__ A) {
    __shared__ float wT[64][64];     // wT[c][o]
    __shared__ float xs[64][256];    // xs[c][px]
    x += (size_t)blockIdx.z * CIN * NPIX;
    A += (size_t)blockIdx.z * OC * NPIX;
    const int tid = threadIdx.x;
    const int pxbase = blockIdx.x * 256;
    const int ocbase = blockIdx.y * 64;

    for (int idx = tid; idx < 1024; idx += 256) {        // 64 oc x 16 float4
        int o = idx >> 4, c4 = idx & 15;
        float4 v = *reinterpret_cast<const float4*>(w + (size_t)(ocbase + o) * CIN + c4 * 4);
        wT[c4 * 4 + 0][o] = v.x; wT[c4 * 4 + 1][o] = v.y;
        wT[c4 * 4 + 2][o] = v.z; wT[c4 * 4 + 3][o] = v.w;
    }
    for (int idx = tid; idx < 4096; idx += 256) {        // 64 c x 64 float4
        int c = idx >> 6, p4 = idx & 63;
        float4 v = *reinterpret_cast<const float4*>(x + (size_t)c * NPIX + pxbase + p4 * 4);
        *reinterpret_cast<float4*>(&xs[c][p4 * 4]) = v;
    }
    __syncthreads();

    const int tx = tid & 15, ty = tid >> 4;
    float acc[4][16];
    #pragma unroll
    for (int a = 0; a < 4; ++a)
        #pragma unroll
        for (int b = 0; b < 16; ++b) acc[a][b] = 0.f;

    #pragma unroll 4
    for (int k = 0; k < 64; ++k) {
        float4 wv = *reinterpret_cast<const float4*>(&wT[k][ty * 4]);
        float wr[4] = {wv.x, wv.y, wv.z, wv.w};
        float xv[16];
        #pragma unroll
        for (int i = 0; i < 4; ++i) {
            float4 v = *reinterpret_cast<const float4*>(&xs[k][tx * 4 + i * 64]);
            xv[i * 4 + 0] = v.x; xv[i * 4 + 1] = v.y;
            xv[i * 4 + 2] = v.z; xv[i * 4 + 3] = v.w;
        }
        #pragma unroll
        for (int a = 0; a < 4; ++a)
            #pragma unroll
            for (int b = 0; b < 16; ++b)
                acc[a][b] = fmaf(wr[a], xv[b], acc[a][b]);
    }

    #pragma unroll
    for (int a = 0; a < 4; ++a) {
        float* Ap = A + (size_t)(ocbase + ty * 4 + a) * NPIX + pxbase;
        #pragma unroll
        for (int i = 0; i < 4; ++i)
            *reinterpret_cast<float4*>(Ap + tx * 4 + i * 64) =
                make_float4(acc[a][i * 4 + 0], acc[a][i * 4 + 1],
                            acc[a][i * 4 + 2], acc[a][i * 4 + 3]);
    }
}

// ---------------- K2: depthwise 3x3, 4 pixels/thread ------------------------
__global__ __launch_bounds__(256)
void k_dw3x3(const float* __restrict__ A, const float* __restrict__ dwv,
             float* __restrict__ Bf) {
    A  += (size_t)blockIdx.z * OC * NPIX;
    Bf += (size_t)blockIdx.z * OC * NPIX;
    int gid = blockIdx.x * 256 + threadIdx.x;
    int ch = gid >> 14;
    int q  = gid & 16383;
    int y  = q >> 6;
    int x4 = (q & 63) << 2;
    const float* Ap = A + (size_t)ch * NPIX;
    float wv[9];
    #pragma unroll
    for (int i = 0; i < 9; ++i) wv[i] = dwv[ch * 9 + i];
    float acc0 = 0.f, acc1 = 0.f, acc2 = 0.f, acc3 = 0.f;
    #pragma unroll
    for (int ky = 0; ky < 3; ++ky) {
        int yy = y + ky - 1;
        if (yy < 0 || yy >= HW) continue;
        const float* row = Ap + yy * HW;
        float cv[6];
        #pragma unroll
        for (int t = 0; t < 6; ++t) {
            int xx = x4 - 1 + t;
            cv[t] = (xx >= 0 && xx < HW) ? row[xx] : 0.f;
        }
        #pragma unroll
        for (int kx = 0; kx < 3; ++kx) {
            float wk = wv[ky * 3 + kx];
            acc0 = fmaf(cv[0 + kx], wk, acc0);
            acc1 = fmaf(cv[1 + kx], wk, acc1);
            acc2 = fmaf(cv[2 + kx], wk, acc2);
            acc3 = fmaf(cv[3 + kx], wk, acc3);
        }
    }
    *reinterpret_cast<float4*>(Bf + (size_t)ch * NPIX + y * HW + x4) =
        make_float4(acc0, acc1, acc2, acc3);
}

// ---------------- K3: fused bilinear-up + windowed cosine attention ---------
// One block per (window, channel). Register-resident K-row/V-col per lane:
// lane l holds K[l][:] and V[:][l]; Q and P rows come in as b128 broadcasts.
__global__ __launch_bounds__(256)
void k_attn(const float* __restrict__ Bf, float* __restrict__ Cf) {
    __shared__ float Qs[PS2 * LSTR];
    __shared__ float Ks[PS2 * LSTR];
    __shared__ float Vs[PS2 * LSTR];
    __shared__ float Ps[4][64];                 // per-wave P row (256B-aligned)
    Bf += (size_t)blockIdx.z * OC * NPIX;
    Cf += (size_t)blockIdx.z * CIN * NPIX_R;
    int n   = blockIdx.x;
    int ch  = n & 63;
    int win = n >> 6;
    int xw  = win / 6;
    int yw  = win - xw * 6;
    const float* qb = Bf + (size_t)ch * NPIX;
    const float* kb = qb + (size_t)64  * NPIX;
    const float* vb = qb + (size_t)128 * NPIX;
    const float scale = 255.0f / 293.0f;        // align_corners=True, 256->294
    int tid = threadIdx.x;

    // phase 1: bilinear gather into LDS with einops permutation
    for (int e = tid; e < PS2 * PS2; e += 256) {
        int rl = e / PS2;
        int cl = e - rl * PS2;
        int gy = xw * PS2 + rl, gx = yw * PS2 + cl;
        float sy = gy * scale, sx = gx * scale;
        int y0 = (int)sy, x0 = (int)sx;
        float ly = sy - y0, lx = sx - x0;
        int y1 = min(y0 + 1, HW - 1), x1 = min(x0 + 1, HW - 1);
        float w00 = (1.f - ly) * (1.f - lx), w01 = (1.f - ly) * lx;
        float w10 = ly * (1.f - lx),         w11 = ly * lx;
        int o00 = y0 * HW + x0, o01 = y0 * HW + x1;
        int o10 = y1 * HW + x0, o11 = y1 * HW + x1;
        int i = (cl / 7) * 7 + (rl % 7);
        int j = (cl % 7) * 7 + (rl / 7);
        int d = i * LSTR + j;
        Qs[d] = qb[o00] * w00 + qb[o01] * w01 + qb[o10] * w10 + qb[o11] * w11;
        Ks[d] = kb[o00] * w00 + kb[o01] * w01 + kb[o10] * w10 + kb[o11] * w11;
        Vs[d] = vb[o00] * w00 + vb[o01] * w01 + vb[o10] * w10 + vb[o11] * w11;
    }
    __syncthreads();

    int wv = tid >> 6, lane = tid & 63;
    int l = (lane < PS2) ? lane : PS2 - 1;      // clamp: lanes 49-63 masked later

    // one-time: K row l -> registers (12 x b128 + 1), lane-local inverse norm
    float kreg[PS2];
    #pragma unroll
    for (int q4 = 0; q4 < 12; ++q4) {
        float4 v = *reinterpret_cast<const float4*>(&Ks[l * LSTR + q4 * 4]);
        kreg[q4 * 4 + 0] = v.x; kreg[q4 * 4 + 1] = v.y;
        kreg[q4 * 4 + 2] = v.z; kreg[q4 * 4 + 3] = v.w;
    }
    kreg[48] = Ks[l * LSTR + 48];
    float kss = 0.f;
    #pragma unroll
    for (int jj = 0; jj < PS2; ++jj) kss = fmaf(kreg[jj], kreg[jj], kss);
    float inkl = 1.f / fmaxf(sqrtf(kss), 1e-12f);

    // one-time: V column l -> registers (consecutive lanes, conflict-free)
    float vcol[PS2];
    #pragma unroll
    for (int i2 = 0; i2 < PS2; ++i2) vcol[i2] = Vs[i2 * LSTR + l];

    for (int i = wv; i < PS2; i += 4) {
        // q-norm: 1 read + shuffle reduce
        float qv = (lane < PS2) ? Qs[i * LSTR + lane] : 0.f;
        float qss = qv * qv;
        #pragma unroll
        for (int off = 32; off; off >>= 1) qss += __shfl_xor(qss, off);
        float inqi = 1.f / fmaxf(sqrtf(qss), 1e-12f);

        // S row: dot(Q[i], K[lane]) via broadcast Q + register K
        float dot = 0.f;
        #pragma unroll
        for (int q4 = 0; q4 < 12; ++q4) {
            float4 qq = *reinterpret_cast<const float4*>(&Qs[i * LSTR + q4 * 4]);
            dot = fmaf(qq.x, kreg[q4 * 4 + 0], dot);
            dot = fmaf(qq.y, kreg[q4 * 4 + 1], dot);
            dot = fmaf(qq.z, kreg[q4 * 4 + 2], dot);
            dot = fmaf(qq.w, kreg[q4 * 4 + 3], dot);
        }
        dot = fmaf(Qs[i * LSTR + 48], kreg[48], dot);
        float sval = (lane < PS2) ? dot * inqi * inkl : -INFINITY;

        // softmax over 49 (lanes >= 49 contribute -inf / 0)
        float m = sval;
        #pragma unroll
        for (int off = 32; off; off >>= 1) m = fmaxf(m, __shfl_xor(m, off));
        float ev = (lane < PS2) ? __expf(sval - m) : 0.f;
        float ssum = ev;
        #pragma unroll
        for (int off = 32; off; off >>= 1) ssum += __shfl_xor(ssum, off);
        Ps[wv][lane] = ev / ssum;               // same-wave write, lockstep

        // out row: broadcast P + register V-col
        float oacc = 0.f;
        #pragma unroll
        for (int p4 = 0; p4 < 12; ++p4) {
            float4 pp = *reinterpret_cast<const float4*>(&Ps[wv][p4 * 4]);
            oacc = fmaf(pp.x, vcol[p4 * 4 + 0], oacc);
            oacc = fmaf(pp.y, vcol[p4 * 4 + 1], oacc);
            oacc = fmaf(pp.z, vcol[p4 * 4 + 2], oacc);
            oacc = fmaf(pp.w, vcol[p4 * 4 + 3], oacc);
        }
        oacc = fmaf(Ps[wv][48], vcol[48], oacc);
        if (lane < PS2) Qs[i * LSTR + lane] = oacc;   // row i owned by this wave
    }
    __syncthreads();

    // inverse window permutation -> resized layout C (64,294,294)
    float* cb = Cf + (size_t)ch * NPIX_R;
    for (int e = tid; e < PS2 * PS2; e += 256) {
        int rl = e / PS2;
        int cl = e - rl * PS2;
        int i = (cl / 7) * 7 + (rl % 7);
        int j = (cl % 7) * 7 + (rl / 7);
        cb[(xw * PS2 + rl) * TH + (yw * PS2 + cl)] = Qs[i * LSTR + j];
    }
}

// ------- K4: bilinear down 294->256 (align_corners=False) + proj ------------
__global__ __launch_bounds__(256)
void k_proj(const float* __restrict__ Cf, const float* __restrict__ pw,
            float* __restrict__ out) {
    Cf  += (size_t)blockIdx.z * CIN * NPIX_R;
    out += (size_t)blockIdx.z * CIN * NPIX;
    int gid  = blockIdx.x * 256 + threadIdx.x;
    int half = gid >> 16;
    int p    = gid & 65535;
    int y = p >> 8, xx = p & 255;
    const float sc = 294.0f / 256.0f;
    float sy = fmaxf((y + 0.5f) * sc - 0.5f, 0.f);
    float sx = fmaxf((xx + 0.5f) * sc - 0.5f, 0.f);
    int y0 = (int)sy, x0 = (int)sx;
    float ly = sy - y0, lx = sx - x0;
    int y1 = min(y0 + 1, TH - 1), x1 = min(x0 + 1, TH - 1);
    float w00 = (1.f - ly) * (1.f - lx), w01 = (1.f - ly) * lx;
    float w10 = ly * (1.f - lx),         w11 = ly * lx;
    int o00 = y0 * TH + x0, o01 = y0 * TH + x1;
    int o10 = y1 * TH + x0, o11 = y1 * TH + x1;
    float rv[CIN];
    #pragma unroll
    for (int c = 0; c < CIN; ++c) {
        const float* cp = Cf + (size_t)c * NPIX_R;
        rv[c] = cp[o00] * w00 + cp[o01] * w01 + cp[o10] * w10 + cp[o11] * w11;
    }
    float* op = out + (size_t)half * 32 * NPIX + p;
    for (int o = 0; o < 32; ++o) {
        const float* wr = pw + (half * 32 + o) * CIN;
        float acc = 0.f;
        #pragma unroll
        for (int c = 0; c < CIN; ++c) acc = fmaf(rv[c], wr[c], acc);
        op[(size_t)o * NPIX] = acc;
    }
}

// ---------------- launch --------------------------------------------------
extern "C" void kernel_launch(void* const* d_in, const int* in_sizes, int n_in,
                              void* d_out, int out_size, void* d_ws, size_t ws_size,
                              hipStream_t stream) {
    const float* x   = (const float*)d_in[0];
    const float* qw  = (const float*)d_in[1];
    const float* dwv = (const float*)d_in[2];
    const float* pw  = (const float*)d_in[3];
    float* out = (float*)d_out;

    const size_t perAB = (size_t)OC * NPIX;
    const size_t needBig = (size_t)2 * BATCH * perAB * sizeof(float);  // 384 MB

    if (ws_size >= needBig) {
        float* A = (float*)d_ws;
        float* B = A + BATCH * perAB;
        float* C = A;
        hipLaunchKernelGGL(k_qkv1x1, dim3(256, 3, BATCH),   dim3(256), 0, stream, x, qw, A);
        hipLaunchKernelGGL(k_dw3x3,  dim3(12288, 1, BATCH), dim3(256), 0, stream, A, dwv, B);
        hipLaunchKernelGGL(k_attn,   dim3(2304, 1, BATCH),  dim3(256), 0, stream, B, C);
        hipLaunchKernelGGL(k_proj,   dim3(512, 1, BATCH),   dim3(256), 0, stream, C, pw, out);
    } else {
        float* A = (float*)d_ws;
        float* B = A + perAB;
        float* C = A;
        for (int b = 0; b < BATCH; ++b) {
            const float* xb = x + (size_t)b * CIN * NPIX;
            float* ob = out + (size_t)b * CIN * NPIX;
            hipLaunchKernelGGL(k_qkv1x1, dim3(256, 3, 1),   dim3(256), 0, stream, xb, qw, A);
            hipLaunchKernelGGL(k_dw3x3,  dim3(12288, 1, 1), dim3(256), 0, stream, A, dwv, B);
            hipLaunchKernelGGL(k_attn,   dim3(2304, 1, 1),  dim3(256), 0, stream, B, C);
            hipLaunchKernelGGL(k_proj,   dim3(512, 1, 1),   dim3(256), 0, stream, C, pw, ob);
        }
    }
}